// Round 2
// baseline (352.002 us; speedup 1.0000x reference)
//
#include <hip/hip_runtime.h>

#define N_NODES 100000
#define W_INF   256
#define W_OUTF  64
#define C_CH    2
#define T_ET    4
#define E_EDGE  800000
#define NUM_CLS 4
#define M_TGT   20000
#define BETA    0.5f
#define MAXDEG  96

typedef __attribute__((ext_vector_type(8))) short bf16x8;
typedef __attribute__((ext_vector_type(4))) float floatx4;

__device__ inline short f2bf(float f) {
    unsigned u = __builtin_bit_cast(unsigned, f);
    u += 0x7FFF + ((u >> 16) & 1);          // RNE
    return (short)(u >> 16);
}
// packed dword q = (bf16 ch0) | (bf16 ch1 << 16)
__device__ inline float bflo(unsigned q) { return __builtin_bit_cast(float, q << 16); }
__device__ inline float bfhi(unsigned q) { return __builtin_bit_cast(float, q & 0xFFFF0000u); }

// ---------- setup: softmax(filt) + Bt convert + mark rid + zero scalars ----------
__global__ void setup_kernel(const float* __restrict__ Ws,
                             const float* __restrict__ conv_weight,
                             const int* __restrict__ target_x,
                             short* __restrict__ Bt, float* __restrict__ filt,
                             int* __restrict__ rid, int* __restrict__ nrows,
                             float* __restrict__ out) {
    int i = blockIdx.x * 256 + threadIdx.x;
    if (i == 0) { *nrows = 0; out[0] = 0.f; }
    if (i < C_CH) {
        int c = i;
        float mx = -1e30f;
        for (int t = 0; t < T_ET; t++) mx = fmaxf(mx, conv_weight[c * T_ET + t]);
        float e[T_ET];
        float s = 0.f;
        for (int t = 0; t < T_ET; t++) { e[t] = expf(conv_weight[c * T_ET + t] - mx); s += e[t]; }
        for (int t = 0; t < T_ET; t++) filt[c * T_ET + t] = e[t] / s;
    }
    if (i < C_CH * W_OUTF * W_INF) {
        int co = i >> 8, k = i & 255;
        int c = co >> 6, o = co & 63;
        Bt[i] = f2bf(Ws[((size_t)c * W_INF + k) * W_OUTF + o]);
    }
    if (i < M_TGT) rid[target_x[i]] = -2;
}

// ---------- compact flagged rows (wave-aggregated atomic) + zero counts ----------
__global__ void compact_kernel(int* __restrict__ rid, int* __restrict__ row_list,
                               int* __restrict__ nrows, int* __restrict__ counts) {
    int n = blockIdx.x * blockDim.x + threadIdx.x;
    if (n < M_TGT) counts[n] = 0;          // consumed by fused build (next dispatch)
    int lane = threadIdx.x & 63;
    bool flag = (n < N_NODES) && (rid[n] == -2);
    unsigned long long mask = __ballot(flag);
    int base = 0;
    if (lane == 0 && mask) base = atomicAdd(nrows, __popcll(mask));
    base = __shfl(base, 0);
    if (flag) {
        int id = base + __popcll(mask & ((1ULL << lane) - 1ULL));
        rid[n] = id;
        row_list[id] = n;
    }
}

// ---------- fused: MFMA gemm (even blocks) + edge binning (odd blocks) ----------
// Interleaved so MFMA waves and scatter waves co-reside on every CU.
// LDS halved to 16.9 KB (B staged in 32-output-row halves) -> ~8 blocks/CU.
// Xp stored bf16, channel-interleaved: dword d = n*64 + o holds {ch0 lo, ch1 hi}.
#define GMT  64
#define BLDA 264
#define GEMM_NB  ((N_NODES + GMT - 1) / GMT)      // 1563
#define BUILD_BX ((E_EDGE / 8 + 255) / 256)       // 391
#define BUILD_TOT (BUILD_BX * T_ET)               // 1564
__global__ __launch_bounds__(256, 6)
void fused_gemm_build(const float* __restrict__ X, const short* __restrict__ Bt,
                      short* __restrict__ Xp,
                      const int* __restrict__ edge_index,
                      const float* __restrict__ edge_value,
                      const int* __restrict__ rid,
                      int* __restrict__ counts,
                      unsigned long long* __restrict__ records) {
    __shared__ short Bl[32][BLDA];     // 16.9 KB
    int tid = threadIdx.x;
    int bx = blockIdx.x;
    if ((bx & 1) == 0) {
        int g = bx >> 1;
        if (g >= GEMM_NB) return;
        int w = tid >> 6, lane = tid & 63;
        int quad = lane >> 4, l15 = lane & 15;
        int m0 = g * GMT + w * 16;
        int arow = m0 + l15;
        if (arow >= N_NODES) arow = N_NODES - 1;
        const float* xrow = X + (size_t)arow * W_INF;
        // preload + convert the wave's full A strip (8 chunks x 8 bf16 = 32 VGPRs)
        bf16x8 af[8];
        #pragma unroll
        for (int kc = 0; kc < 8; kc++) {
            int kb = kc * 32 + quad * 8;
            float4 v0 = *(const float4*)&xrow[kb];
            float4 v1 = *(const float4*)&xrow[kb + 4];
            af[kc][0] = f2bf(v0.x); af[kc][1] = f2bf(v0.y);
            af[kc][2] = f2bf(v0.z); af[kc][3] = f2bf(v0.w);
            af[kc][4] = f2bf(v1.x); af[kc][5] = f2bf(v1.y);
            af[kc][6] = f2bf(v1.z); af[kc][7] = f2bf(v1.w);
        }
        floatx4 acc[C_CH][4] = {};
        #pragma unroll 1
        for (int ch = 0; ch < 4; ch++) {          // c = ch>>1, half h = ch&1
            int c = ch >> 1, h = ch & 1;
            if (ch) __syncthreads();   // protect re-stage
            // stage 32 B-rows x 256 k: 1024 bf16x8 chunks, 4 per thread
            #pragma unroll
            for (int l = 0; l < 4; l++) {
                int idx = tid + l * 256;
                int r = idx >> 5;
                int kp = (idx & 31) * 8;
                *(bf16x8*)&Bl[r][kp] =
                    *(const bf16x8*)&Bt[(size_t)(c * 64 + h * 32 + r) * W_INF + kp];
            }
            __syncthreads();
            #pragma unroll
            for (int kc = 0; kc < 8; kc++) {
                int kb = kc * 32 + quad * 8;
                #pragma unroll
                for (int nt = 0; nt < 2; nt++) {
                    bf16x8 b = *(bf16x8*)&Bl[nt * 16 + l15][kb];
                    acc[c][h * 2 + nt] =
                        __builtin_amdgcn_mfma_f32_16x16x32_bf16(af[kc], b, acc[c][h * 2 + nt], 0, 0, 0);
                }
            }
        }
        // D layout: j = h*2+nt -> o = h*32 + nt*16 + l15; m = m0 + quad*4 + r
        #pragma unroll
        for (int j = 0; j < 4; j++) {
            int o = (j >> 1) * 32 + (j & 1) * 16 + l15;
            #pragma unroll
            for (int r = 0; r < 4; r++) {
                int m = m0 + quad * 4 + r;
                if (m < N_NODES) {
                    unsigned pk = (unsigned)(unsigned short)f2bf(acc[0][j][r])
                                | ((unsigned)(unsigned short)f2bf(acc[1][j][r]) << 16);
                    *(unsigned*)&Xp[(size_t)m * (C_CH * W_OUTF) + o * 2] = pk;
                }
            }
        }
    } else {
        int bb = bx >> 1;                         // 0..BUILD_TOT-1
        int t = bb / BUILD_BX;
        int i = (bb - t * BUILD_BX) * 256 + tid;  // oct-edge index
        if (i >= E_EDGE / 8) return;
        int e = i * 8;
        const int*   rbase = &edge_index[(size_t)(t * 2 + 0) * E_EDGE + e];
        const int*   cbase = &edge_index[(size_t)(t * 2 + 1) * E_EDGE + e];
        const float* vbase = &edge_value[(size_t)t * E_EDGE + e];
        int4   r4a = *(const int4*)  &rbase[0], r4b = *(const int4*)  &rbase[4];
        int4   c4a = *(const int4*)  &cbase[0], c4b = *(const int4*)  &cbase[4];
        float4 v4a = *(const float4*)&vbase[0], v4b = *(const float4*)&vbase[4];
        int rows[8] = {r4a.x, r4a.y, r4a.z, r4a.w, r4b.x, r4b.y, r4b.z, r4b.w};
        int cols[8] = {c4a.x, c4a.y, c4a.z, c4a.w, c4b.x, c4b.y, c4b.z, c4b.w};
        float evv[8] = {v4a.x, v4a.y, v4a.z, v4a.w, v4b.x, v4b.y, v4b.z, v4b.w};
        int ids[8];
        #pragma unroll
        for (int j = 0; j < 8; j++) ids[j] = rid[rows[j]];
        #pragma unroll
        for (int j = 0; j < 8; j++) {
            if (ids[j] >= 0) {
                int p = atomicAdd(&counts[ids[j]], 1);
                if (p < MAXDEG) {
                    unsigned long long rec =
                        (unsigned long long)(unsigned)(cols[j] | (t << 20)) |
                        ((unsigned long long)__float_as_uint(evv[j]) << 32);
                    records[(size_t)ids[j] * MAXDEG + p] = rec;
                }
            }
        }
    }
}

// ---------- gather + relu fuse: one wave per row, both channels per lane ----------
// Xp dword d = node*64 + lane holds both channels -> one coalesced 256B read/edge.
// 8-deep unroll: one full 64B record line + 8 independent row reads in flight.
__global__ void gather_kernel(const int* __restrict__ row_list,
                              const int* __restrict__ counts,
                              const unsigned long long* __restrict__ records,
                              const float* __restrict__ filt,
                              const short* __restrict__ Xp,
                              float* __restrict__ Hcat,
                              const int* __restrict__ nrows_ptr) {
    int w = threadIdx.x >> 6, lane = threadIdx.x & 63;
    int b = blockIdx.x * 4 + w;
    if (b >= *nrows_ptr) return;
    float f0[T_ET], f1[T_ET];
    #pragma unroll
    for (int t = 0; t < T_ET; t++) { f0[t] = filt[t]; f1[t] = filt[T_ET + t]; }
    int n = row_list[b];
    int cnt = counts[b]; if (cnt > MAXDEG) cnt = MAXDEG;
    const unsigned long long* rec = records + (size_t)b * MAXDEG;
    const unsigned* xb = (const unsigned*)Xp + lane;
    float a0 = 0.f, a1 = 0.f;
    int p = 0;
    for (; p + 7 < cnt; p += 8) {
        unsigned long long rr[8];
        #pragma unroll
        for (int j = 0; j < 8; j++) rr[j] = rec[p + j];
        unsigned q[8];
        #pragma unroll
        for (int j = 0; j < 8; j++)
            q[j] = xb[(size_t)((unsigned)rr[j] & 0xFFFFF) * 64];
        #pragma unroll
        for (int j = 0; j < 8; j++) {
            int t = (int)((unsigned)rr[j] >> 20);
            float e = __uint_as_float((unsigned)(rr[j] >> 32));
            a0 += e * f0[t] * bflo(q[j]);
            a1 += e * f1[t] * bfhi(q[j]);
        }
    }
    for (; p + 3 < cnt; p += 4) {
        unsigned long long rr[4];
        #pragma unroll
        for (int j = 0; j < 4; j++) rr[j] = rec[p + j];
        #pragma unroll
        for (int j = 0; j < 4; j++) {
            unsigned q = xb[(size_t)((unsigned)rr[j] & 0xFFFFF) * 64];
            int t = (int)((unsigned)rr[j] >> 20);
            float e = __uint_as_float((unsigned)(rr[j] >> 32));
            a0 += e * f0[t] * bflo(q);
            a1 += e * f1[t] * bfhi(q);
        }
    }
    for (; p < cnt; p++) {
        unsigned long long r0 = rec[p];
        int k0 = (int)(unsigned)r0;
        float e0 = __uint_as_float((unsigned)(r0 >> 32));
        unsigned q0 = xb[(size_t)(k0 & 0xFFFFF) * 64];
        int t0 = k0 >> 20;
        a0 += e0 * f0[t0] * bflo(q0);
        a1 += e0 * f1[t0] * bfhi(q0);
    }
    unsigned qn = xb[(size_t)n * 64];
    float h0 = BETA * bflo(qn) + (1.f - BETA) * a0;
    float h1 = BETA * bfhi(qn) + (1.f - BETA) * a1;
    Hcat[(size_t)b * (C_CH * W_OUTF) + lane]          = fmaxf(h0, 0.f);
    Hcat[(size_t)b * (C_CH * W_OUTF) + W_OUTF + lane] = fmaxf(h1, 0.f);
}

// ---------- head: reads compacted Hcat via rid ----------
#define HTGT 16
__global__ void head_kernel(const float* __restrict__ Hcat,
                            const int* __restrict__ rid,
                            const float* __restrict__ W1,
                            const float* __restrict__ b1,
                            const float* __restrict__ linW,
                            const float* __restrict__ linb,
                            const int* __restrict__ target_x,
                            const int* __restrict__ target,
                            float* __restrict__ out) {
    __shared__ float w1s[C_CH * W_OUTF][W_OUTF + 1];
    __shared__ float hcat_s[4][C_CH * W_OUTF];
    __shared__ float loss_s[4];
    int tid = threadIdx.x;
    for (int i = tid; i < W_OUTF * C_CH * W_OUTF; i += 256) {
        int o = i >> 7, k = i & 127;
        w1s[k][o] = W1[i];
    }
    int wave = tid >> 6, lane = tid & 63;
    float l0 = linW[0 * W_OUTF + lane], l1 = linW[1 * W_OUTF + lane];
    float l2 = linW[2 * W_OUTF + lane], l3 = linW[3 * W_OUTF + lane];
    float lb0 = linb[0], lb1 = linb[1], lb2 = linb[2], lb3 = linb[3];
    float bias = b1[lane];
    float lsum = 0.f;
    __syncthreads();
    for (int it = 0; it < HTGT / 4; it++) {
        int m = blockIdx.x * HTGT + it * 4 + wave;
        int row = target_x[m];
        int id = rid[row];
        hcat_s[wave][lane]      = Hcat[(size_t)id * (C_CH * W_OUTF) + lane];
        hcat_s[wave][64 + lane] = Hcat[(size_t)id * (C_CH * W_OUTF) + 64 + lane];
        __syncthreads();
        float acc = bias;
        #pragma unroll 8
        for (int k = 0; k < C_CH * W_OUTF; k++) acc += hcat_s[wave][k] * w1s[k][lane];
        float h2 = fmaxf(acc, 0.f);
        float p0 = l0 * h2, p1 = l1 * h2, p2 = l2 * h2, p3 = l3 * h2;
        #pragma unroll
        for (int off = 32; off > 0; off >>= 1) {
            p0 += __shfl_xor(p0, off);
            p1 += __shfl_xor(p1, off);
            p2 += __shfl_xor(p2, off);
            p3 += __shfl_xor(p3, off);
        }
        if (lane == 0) {
            float y[NUM_CLS];
            y[0] = p0 + lb0; y[1] = p1 + lb1; y[2] = p2 + lb2; y[3] = p3 + lb3;
            float mx = fmaxf(fmaxf(y[0], y[1]), fmaxf(y[2], y[3]));
            float s = 0.f;
            #pragma unroll
            for (int k = 0; k < NUM_CLS; k++) s += expf(y[k] - mx);
            float lse = mx + logf(s);
            #pragma unroll
            for (int k = 0; k < NUM_CLS; k++) out[1 + (size_t)m * NUM_CLS + k] = y[k];
            int tg = target[m];
            lsum += lse - y[tg];
        }
        __syncthreads();
    }
    if (lane == 0) loss_s[wave] = lsum;
    __syncthreads();
    if (tid == 0) {
        float L = loss_s[0] + loss_s[1] + loss_s[2] + loss_s[3];
        atomicAdd(&out[0], L * (1.0f / (float)M_TGT));
    }
}

extern "C" void kernel_launch(void* const* d_in, const int* in_sizes, int n_in,
                              void* d_out, int out_size, void* d_ws, size_t ws_size,
                              hipStream_t stream) {
    const float* X           = (const float*)d_in[0];
    const float* edge_value  = (const float*)d_in[1];
    const float* Ws          = (const float*)d_in[2];
    const float* conv_weight = (const float*)d_in[3];
    const float* linear1_W   = (const float*)d_in[4];
    const float* linear1_b   = (const float*)d_in[5];
    const float* lin_W       = (const float*)d_in[6];
    const float* lin_b       = (const float*)d_in[7];
    const int*   edge_index  = (const int*)d_in[8];
    const int*   target_x    = (const int*)d_in[9];
    const int*   target      = (const int*)d_in[10];
    float* out = (float*)d_out;

    char* ws = (char*)d_ws;
    size_t off = 0;
    float* filt  = (float*)(ws + off); off += 256;
    size_t xbytes = (size_t)N_NODES * C_CH * W_OUTF * sizeof(short);  // 25.6 MB bf16
    short* Xp    = (short*)(ws + off); off += xbytes;
    float* Hcat  = (float*)(ws + off); off += (size_t)M_TGT * C_CH * W_OUTF * sizeof(float);
    unsigned long long* records = (unsigned long long*)(ws + off);
    off += (size_t)M_TGT * MAXDEG * sizeof(unsigned long long);       // 15.4 MB
    short* Bt    = (short*)(ws + off); off += (size_t)C_CH * W_OUTF * W_INF * sizeof(short);
    int*   rid   = (int*)  (ws + off); off += (size_t)N_NODES * sizeof(int);
    int*   row_list = (int*)(ws + off); off += (size_t)M_TGT * sizeof(int);
    int*   counts   = (int*)(ws + off); off += (size_t)M_TGT * sizeof(int);
    int*   nrows    = (int*)(ws + off); off += 256;

    hipMemsetAsync(rid, 0xFF, (size_t)N_NODES * sizeof(int), stream);   // -1

    setup_kernel<<<128, 256, 0, stream>>>(Ws, conv_weight, target_x, Bt, filt, rid, nrows, out);
    compact_kernel<<<(N_NODES + 255) / 256, 256, 0, stream>>>(rid, row_list, nrows, counts);
    fused_gemm_build<<<2 * BUILD_TOT, 256, 0, stream>>>(
        X, Bt, Xp, edge_index, edge_value, rid, counts, records);
    gather_kernel<<<(M_TGT + 3) / 4, 256, 0, stream>>>(row_list, counts, records, filt, Xp, Hcat, nrows);
    head_kernel<<<M_TGT / HTGT, 256, 0, stream>>>(Hcat, rid, linear1_W, linear1_b, lin_W, lin_b,
                                                  target_x, target, out);
}

// Round 3
// 343.358 us; speedup vs baseline: 1.0252x; 1.0252x over previous
//
#include <hip/hip_runtime.h>

#define N_NODES 100000
#define W_INF   256
#define W_OUTF  64
#define C_CH    2
#define T_ET    4
#define E_EDGE  800000
#define NUM_CLS 4
#define M_TGT   20000
#define BETA    0.5f
#define MAXDEG  96

typedef __attribute__((ext_vector_type(8))) short bf16x8;
typedef __attribute__((ext_vector_type(4))) float floatx4;

__device__ inline short f2bf(float f) {
    unsigned u = __builtin_bit_cast(unsigned, f);
    u += 0x7FFF + ((u >> 16) & 1);          // RNE
    return (short)(u >> 16);
}
// packed dword q = (bf16 ch0) | (bf16 ch1 << 16)
__device__ inline float bflo(unsigned q) { return __builtin_bit_cast(float, q << 16); }
__device__ inline float bfhi(unsigned q) { return __builtin_bit_cast(float, q & 0xFFFF0000u); }

// ---------- setup: softmax(filt) + Bt convert + mark rid + zero scalars ----------
__global__ void setup_kernel(const float* __restrict__ Ws,
                             const float* __restrict__ conv_weight,
                             const int* __restrict__ target_x,
                             short* __restrict__ Bt, float* __restrict__ filt,
                             int* __restrict__ rid, int* __restrict__ nrows,
                             float* __restrict__ out) {
    int i = blockIdx.x * 256 + threadIdx.x;
    if (i == 0) { *nrows = 0; out[0] = 0.f; }
    if (i < C_CH) {
        int c = i;
        float mx = -1e30f;
        for (int t = 0; t < T_ET; t++) mx = fmaxf(mx, conv_weight[c * T_ET + t]);
        float e[T_ET];
        float s = 0.f;
        for (int t = 0; t < T_ET; t++) { e[t] = expf(conv_weight[c * T_ET + t] - mx); s += e[t]; }
        for (int t = 0; t < T_ET; t++) filt[c * T_ET + t] = e[t] / s;
    }
    if (i < C_CH * W_OUTF * W_INF) {
        int co = i >> 8, k = i & 255;
        int c = co >> 6, o = co & 63;
        Bt[i] = f2bf(Ws[((size_t)c * W_INF + k) * W_OUTF + o]);
    }
    if (i < M_TGT) rid[target_x[i]] = -2;
}

// ---------- compact flagged rows (wave-aggregated atomic) + zero counts ----------
__global__ void compact_kernel(int* __restrict__ rid, int* __restrict__ row_list,
                               int* __restrict__ nrows, int* __restrict__ counts) {
    int n = blockIdx.x * blockDim.x + threadIdx.x;
    if (n < M_TGT) counts[n] = 0;          // consumed by fused build (next dispatch)
    int lane = threadIdx.x & 63;
    bool flag = (n < N_NODES) && (rid[n] == -2);
    unsigned long long mask = __ballot(flag);
    int base = 0;
    if (lane == 0 && mask) base = atomicAdd(nrows, __popcll(mask));
    base = __shfl(base, 0);
    if (flag) {
        int id = base + __popcll(mask & ((1ULL << lane) - 1ULL));
        rid[n] = id;
        row_list[id] = n;
    }
}

// ---------- fused: MFMA gemm (blocks [0,GEMM_NB)) + edge binning (rest) ----------
// LDS 16.9 KB (B staged in 32-output-row halves, 4 stages); launch_bounds(256,4)
// keeps the register allocator at <=128 regs -> NO spill (R2 lesson: (256,6)
// clamped to ~85 and spilled acc/af -> +150MB scratch traffic).
// Xp stored bf16, channel-interleaved: dword d = n*64 + o holds {ch0 lo, ch1 hi}.
#define GMT  64
#define BLDA 264
#define GEMM_NB  ((N_NODES + GMT - 1) / GMT)      // 1563
#define BUILD_BX ((E_EDGE / 8 + 255) / 256)       // 391
#define BUILD_TOT (BUILD_BX * T_ET)               // 1564
__global__ __launch_bounds__(256, 4)
void fused_gemm_build(const float* __restrict__ X, const short* __restrict__ Bt,
                      short* __restrict__ Xp,
                      const int* __restrict__ edge_index,
                      const float* __restrict__ edge_value,
                      const int* __restrict__ rid,
                      int* __restrict__ counts,
                      unsigned long long* __restrict__ records) {
    __shared__ short Bl[32][BLDA];     // 16.9 KB
    int tid = threadIdx.x;
    int bx = blockIdx.x;
    if (bx < GEMM_NB) {
        int w = tid >> 6, lane = tid & 63;
        int quad = lane >> 4, l15 = lane & 15;
        int m0 = bx * GMT + w * 16;
        int arow = m0 + l15;
        if (arow >= N_NODES) arow = N_NODES - 1;
        const float* xrow = X + (size_t)arow * W_INF;
        // preload + convert the wave's full A strip (8 chunks x 8 bf16 = 32 VGPRs)
        bf16x8 af[8];
        #pragma unroll
        for (int kc = 0; kc < 8; kc++) {
            int kb = kc * 32 + quad * 8;
            float4 v0 = *(const float4*)&xrow[kb];
            float4 v1 = *(const float4*)&xrow[kb + 4];
            af[kc][0] = f2bf(v0.x); af[kc][1] = f2bf(v0.y);
            af[kc][2] = f2bf(v0.z); af[kc][3] = f2bf(v0.w);
            af[kc][4] = f2bf(v1.x); af[kc][5] = f2bf(v1.y);
            af[kc][6] = f2bf(v1.z); af[kc][7] = f2bf(v1.w);
        }
        floatx4 acc[C_CH][4] = {};
        #pragma unroll 1
        for (int ch = 0; ch < 4; ch++) {          // c = ch>>1, half h = ch&1
            int c = ch >> 1, h = ch & 1;
            if (ch) __syncthreads();   // protect re-stage
            // stage 32 B-rows x 256 k: 1024 bf16x8 chunks, 4 per thread
            #pragma unroll
            for (int l = 0; l < 4; l++) {
                int idx = tid + l * 256;
                int r = idx >> 5;
                int kp = (idx & 31) * 8;
                *(bf16x8*)&Bl[r][kp] =
                    *(const bf16x8*)&Bt[(size_t)(c * 64 + h * 32 + r) * W_INF + kp];
            }
            __syncthreads();
            #pragma unroll
            for (int kc = 0; kc < 8; kc++) {
                int kb = kc * 32 + quad * 8;
                #pragma unroll
                for (int nt = 0; nt < 2; nt++) {
                    bf16x8 b = *(bf16x8*)&Bl[nt * 16 + l15][kb];
                    acc[c][h * 2 + nt] =
                        __builtin_amdgcn_mfma_f32_16x16x32_bf16(af[kc], b, acc[c][h * 2 + nt], 0, 0, 0);
                }
            }
        }
        // D layout: j = h*2+nt -> o = h*32 + nt*16 + l15; m = m0 + quad*4 + r
        #pragma unroll
        for (int j = 0; j < 4; j++) {
            int o = (j >> 1) * 32 + (j & 1) * 16 + l15;
            #pragma unroll
            for (int r = 0; r < 4; r++) {
                int m = m0 + quad * 4 + r;
                if (m < N_NODES) {
                    unsigned pk = (unsigned)(unsigned short)f2bf(acc[0][j][r])
                                | ((unsigned)(unsigned short)f2bf(acc[1][j][r]) << 16);
                    *(unsigned*)&Xp[(size_t)m * (C_CH * W_OUTF) + o * 2] = pk;
                }
            }
        }
    } else {
        int bb = bx - GEMM_NB;                    // 0..BUILD_TOT-1
        int t = bb / BUILD_BX;
        int i = (bb - t * BUILD_BX) * 256 + tid;  // oct-edge index
        if (i >= E_EDGE / 8) return;
        int e = i * 8;
        const int*   rbase = &edge_index[(size_t)(t * 2 + 0) * E_EDGE + e];
        const int*   cbase = &edge_index[(size_t)(t * 2 + 1) * E_EDGE + e];
        const float* vbase = &edge_value[(size_t)t * E_EDGE + e];
        int4   r4a = *(const int4*)  &rbase[0], r4b = *(const int4*)  &rbase[4];
        int4   c4a = *(const int4*)  &cbase[0], c4b = *(const int4*)  &cbase[4];
        float4 v4a = *(const float4*)&vbase[0], v4b = *(const float4*)&vbase[4];
        int rows[8] = {r4a.x, r4a.y, r4a.z, r4a.w, r4b.x, r4b.y, r4b.z, r4b.w};
        int cols[8] = {c4a.x, c4a.y, c4a.z, c4a.w, c4b.x, c4b.y, c4b.z, c4b.w};
        float evv[8] = {v4a.x, v4a.y, v4a.z, v4a.w, v4b.x, v4b.y, v4b.z, v4b.w};
        int ids[8];
        #pragma unroll
        for (int j = 0; j < 8; j++) ids[j] = rid[rows[j]];
        #pragma unroll
        for (int j = 0; j < 8; j++) {
            if (ids[j] >= 0) {
                int p = atomicAdd(&counts[ids[j]], 1);
                if (p < MAXDEG) {
                    unsigned long long rec =
                        (unsigned long long)(unsigned)(cols[j] | (t << 20)) |
                        ((unsigned long long)__float_as_uint(evv[j]) << 32);
                    records[(size_t)ids[j] * MAXDEG + p] = rec;
                }
            }
        }
    }
}

// ---------- gather + relu fuse: one wave per row, both channels per lane ----------
// Xp dword d = node*64 + lane holds both channels -> one coalesced 256B read/edge.
// 8-deep unroll: one full 64B record line + 8 independent row reads in flight.
__global__ void gather_kernel(const int* __restrict__ row_list,
                              const int* __restrict__ counts,
                              const unsigned long long* __restrict__ records,
                              const float* __restrict__ filt,
                              const short* __restrict__ Xp,
                              float* __restrict__ Hcat,
                              const int* __restrict__ nrows_ptr) {
    int w = threadIdx.x >> 6, lane = threadIdx.x & 63;
    int b = blockIdx.x * 4 + w;
    if (b >= *nrows_ptr) return;
    float f0[T_ET], f1[T_ET];
    #pragma unroll
    for (int t = 0; t < T_ET; t++) { f0[t] = filt[t]; f1[t] = filt[T_ET + t]; }
    int n = row_list[b];
    int cnt = counts[b]; if (cnt > MAXDEG) cnt = MAXDEG;
    const unsigned long long* rec = records + (size_t)b * MAXDEG;
    const unsigned* xb = (const unsigned*)Xp + lane;
    float a0 = 0.f, a1 = 0.f;
    int p = 0;
    for (; p + 7 < cnt; p += 8) {
        unsigned long long rr[8];
        #pragma unroll
        for (int j = 0; j < 8; j++) rr[j] = rec[p + j];
        unsigned q[8];
        #pragma unroll
        for (int j = 0; j < 8; j++)
            q[j] = xb[(size_t)((unsigned)rr[j] & 0xFFFFF) * 64];
        #pragma unroll
        for (int j = 0; j < 8; j++) {
            int t = (int)((unsigned)rr[j] >> 20);
            float e = __uint_as_float((unsigned)(rr[j] >> 32));
            a0 += e * f0[t] * bflo(q[j]);
            a1 += e * f1[t] * bfhi(q[j]);
        }
    }
    for (; p + 3 < cnt; p += 4) {
        unsigned long long rr[4];
        #pragma unroll
        for (int j = 0; j < 4; j++) rr[j] = rec[p + j];
        #pragma unroll
        for (int j = 0; j < 4; j++) {
            unsigned q = xb[(size_t)((unsigned)rr[j] & 0xFFFFF) * 64];
            int t = (int)((unsigned)rr[j] >> 20);
            float e = __uint_as_float((unsigned)(rr[j] >> 32));
            a0 += e * f0[t] * bflo(q);
            a1 += e * f1[t] * bfhi(q);
        }
    }
    for (; p < cnt; p++) {
        unsigned long long r0 = rec[p];
        int k0 = (int)(unsigned)r0;
        float e0 = __uint_as_float((unsigned)(r0 >> 32));
        unsigned q0 = xb[(size_t)(k0 & 0xFFFFF) * 64];
        int t0 = k0 >> 20;
        a0 += e0 * f0[t0] * bflo(q0);
        a1 += e0 * f1[t0] * bfhi(q0);
    }
    unsigned qn = xb[(size_t)n * 64];
    float h0 = BETA * bflo(qn) + (1.f - BETA) * a0;
    float h1 = BETA * bfhi(qn) + (1.f - BETA) * a1;
    Hcat[(size_t)b * (C_CH * W_OUTF) + lane]          = fmaxf(h0, 0.f);
    Hcat[(size_t)b * (C_CH * W_OUTF) + W_OUTF + lane] = fmaxf(h1, 0.f);
}

// ---------- head: reads compacted Hcat via rid ----------
#define HTGT 16
__global__ void head_kernel(const float* __restrict__ Hcat,
                            const int* __restrict__ rid,
                            const float* __restrict__ W1,
                            const float* __restrict__ b1,
                            const float* __restrict__ linW,
                            const float* __restrict__ linb,
                            const int* __restrict__ target_x,
                            const int* __restrict__ target,
                            float* __restrict__ out) {
    __shared__ float w1s[C_CH * W_OUTF][W_OUTF + 1];
    __shared__ float hcat_s[4][C_CH * W_OUTF];
    __shared__ float loss_s[4];
    int tid = threadIdx.x;
    for (int i = tid; i < W_OUTF * C_CH * W_OUTF; i += 256) {
        int o = i >> 7, k = i & 127;
        w1s[k][o] = W1[i];
    }
    int wave = tid >> 6, lane = tid & 63;
    float l0 = linW[0 * W_OUTF + lane], l1 = linW[1 * W_OUTF + lane];
    float l2 = linW[2 * W_OUTF + lane], l3 = linW[3 * W_OUTF + lane];
    float lb0 = linb[0], lb1 = linb[1], lb2 = linb[2], lb3 = linb[3];
    float bias = b1[lane];
    float lsum = 0.f;
    __syncthreads();
    for (int it = 0; it < HTGT / 4; it++) {
        int m = blockIdx.x * HTGT + it * 4 + wave;
        int row = target_x[m];
        int id = rid[row];
        hcat_s[wave][lane]      = Hcat[(size_t)id * (C_CH * W_OUTF) + lane];
        hcat_s[wave][64 + lane] = Hcat[(size_t)id * (C_CH * W_OUTF) + 64 + lane];
        __syncthreads();
        float acc = bias;
        #pragma unroll 8
        for (int k = 0; k < C_CH * W_OUTF; k++) acc += hcat_s[wave][k] * w1s[k][lane];
        float h2 = fmaxf(acc, 0.f);
        float p0 = l0 * h2, p1 = l1 * h2, p2 = l2 * h2, p3 = l3 * h2;
        #pragma unroll
        for (int off = 32; off > 0; off >>= 1) {
            p0 += __shfl_xor(p0, off);
            p1 += __shfl_xor(p1, off);
            p2 += __shfl_xor(p2, off);
            p3 += __shfl_xor(p3, off);
        }
        if (lane == 0) {
            float y[NUM_CLS];
            y[0] = p0 + lb0; y[1] = p1 + lb1; y[2] = p2 + lb2; y[3] = p3 + lb3;
            float mx = fmaxf(fmaxf(y[0], y[1]), fmaxf(y[2], y[3]));
            float s = 0.f;
            #pragma unroll
            for (int k = 0; k < NUM_CLS; k++) s += expf(y[k] - mx);
            float lse = mx + logf(s);
            #pragma unroll
            for (int k = 0; k < NUM_CLS; k++) out[1 + (size_t)m * NUM_CLS + k] = y[k];
            int tg = target[m];
            lsum += lse - y[tg];
        }
        __syncthreads();
    }
    if (lane == 0) loss_s[wave] = lsum;
    __syncthreads();
    if (tid == 0) {
        float L = loss_s[0] + loss_s[1] + loss_s[2] + loss_s[3];
        atomicAdd(&out[0], L * (1.0f / (float)M_TGT));
    }
}

extern "C" void kernel_launch(void* const* d_in, const int* in_sizes, int n_in,
                              void* d_out, int out_size, void* d_ws, size_t ws_size,
                              hipStream_t stream) {
    const float* X           = (const float*)d_in[0];
    const float* edge_value  = (const float*)d_in[1];
    const float* Ws          = (const float*)d_in[2];
    const float* conv_weight = (const float*)d_in[3];
    const float* linear1_W   = (const float*)d_in[4];
    const float* linear1_b   = (const float*)d_in[5];
    const float* lin_W       = (const float*)d_in[6];
    const float* lin_b       = (const float*)d_in[7];
    const int*   edge_index  = (const int*)d_in[8];
    const int*   target_x    = (const int*)d_in[9];
    const int*   target      = (const int*)d_in[10];
    float* out = (float*)d_out;

    char* ws = (char*)d_ws;
    size_t off = 0;
    float* filt  = (float*)(ws + off); off += 256;
    size_t xbytes = (size_t)N_NODES * C_CH * W_OUTF * sizeof(short);  // 25.6 MB bf16
    short* Xp    = (short*)(ws + off); off += xbytes;
    float* Hcat  = (float*)(ws + off); off += (size_t)M_TGT * C_CH * W_OUTF * sizeof(float);
    unsigned long long* records = (unsigned long long*)(ws + off);
    off += (size_t)M_TGT * MAXDEG * sizeof(unsigned long long);       // 15.4 MB
    short* Bt    = (short*)(ws + off); off += (size_t)C_CH * W_OUTF * W_INF * sizeof(short);
    int*   rid   = (int*)  (ws + off); off += (size_t)N_NODES * sizeof(int);
    int*   row_list = (int*)(ws + off); off += (size_t)M_TGT * sizeof(int);
    int*   counts   = (int*)(ws + off); off += (size_t)M_TGT * sizeof(int);
    int*   nrows    = (int*)(ws + off); off += 256;

    hipMemsetAsync(rid, 0xFF, (size_t)N_NODES * sizeof(int), stream);   // -1

    setup_kernel<<<128, 256, 0, stream>>>(Ws, conv_weight, target_x, Bt, filt, rid, nrows, out);
    compact_kernel<<<(N_NODES + 255) / 256, 256, 0, stream>>>(rid, row_list, nrows, counts);
    fused_gemm_build<<<GEMM_NB + BUILD_TOT, 256, 0, stream>>>(
        X, Bt, Xp, edge_index, edge_value, rid, counts, records);
    gather_kernel<<<(M_TGT + 3) / 4, 256, 0, stream>>>(row_list, counts, records, filt, Xp, Hcat, nrows);
    head_kernel<<<M_TGT / HTGT, 256, 0, stream>>>(Hcat, rid, linear1_W, linear1_b, lin_W, lin_b,
                                                  target_x, target, out);
}

// Round 4
// 319.995 us; speedup vs baseline: 1.1000x; 1.0730x over previous
//
#include <hip/hip_runtime.h>

#define N_NODES 100000
#define W_INF   256
#define W_OUTF  64
#define C_CH    2
#define T_ET    4
#define E_EDGE  800000
#define NUM_CLS 4
#define M_TGT   20000
#define BETA    0.5f
#define MAXDEG  96

typedef __attribute__((ext_vector_type(8))) short bf16x8;
typedef __attribute__((ext_vector_type(4))) float floatx4;

__device__ inline short f2bf(float f) {
    unsigned u = __builtin_bit_cast(unsigned, f);
    u += 0x7FFF + ((u >> 16) & 1);          // RNE
    return (short)(u >> 16);
}
// packed dword q = (bf16 ch0) | (bf16 ch1 << 16)
__device__ inline float bflo(unsigned q) { return __builtin_bit_cast(float, q << 16); }
__device__ inline float bfhi(unsigned q) { return __builtin_bit_cast(float, q & 0xFFFF0000u); }

// ---------- setup: softmax(filt) + Bt convert + mark rid + zero scalars ----------
__global__ void setup_kernel(const float* __restrict__ Ws,
                             const float* __restrict__ conv_weight,
                             const int* __restrict__ target_x,
                             short* __restrict__ Bt, float* __restrict__ filt,
                             int* __restrict__ rid, int* __restrict__ nrows,
                             float* __restrict__ out) {
    int i = blockIdx.x * 256 + threadIdx.x;
    if (i == 0) { *nrows = 0; out[0] = 0.f; }
    if (i < C_CH) {
        int c = i;
        float mx = -1e30f;
        for (int t = 0; t < T_ET; t++) mx = fmaxf(mx, conv_weight[c * T_ET + t]);
        float e[T_ET];
        float s = 0.f;
        for (int t = 0; t < T_ET; t++) { e[t] = expf(conv_weight[c * T_ET + t] - mx); s += e[t]; }
        for (int t = 0; t < T_ET; t++) filt[c * T_ET + t] = e[t] / s;
    }
    if (i < C_CH * W_OUTF * W_INF) {
        int co = i >> 8, k = i & 255;
        int c = co >> 6, o = co & 63;
        Bt[i] = f2bf(Ws[((size_t)c * W_INF + k) * W_OUTF + o]);
    }
    if (i < M_TGT) rid[target_x[i]] = -2;
}

// ---------- compact flagged rows (wave-aggregated atomic) + zero counts ----------
__global__ void compact_kernel(int* __restrict__ rid, int* __restrict__ row_list,
                               int* __restrict__ nrows, int* __restrict__ counts) {
    int n = blockIdx.x * blockDim.x + threadIdx.x;
    if (n < M_TGT) counts[n] = 0;          // consumed by fused build (next dispatch)
    int lane = threadIdx.x & 63;
    bool flag = (n < N_NODES) && (rid[n] == -2);
    unsigned long long mask = __ballot(flag);
    int base = 0;
    if (lane == 0 && mask) base = atomicAdd(nrows, __popcll(mask));
    base = __shfl(base, 0);
    if (flag) {
        int id = base + __popcll(mask & ((1ULL << lane) - 1ULL));
        rid[n] = id;
        row_list[id] = n;
    }
}

// ---------- fused: MFMA gemm (blocks [0,GEMM_NB)) + edge binning (rest) ----------
// R3 lesson (rule #20): acc[] must be STATICALLY indexed everywhere — the
// runtime-ch-loop version put acc in scratch (VGPR_Count 40, +150MB traffic).
// Here: kh loop (#pragma unroll 1) touches addresses only; c/nt/kc loops are
// fully unrolled. af[4] per K-half (16 VGPRs) keeps steady-state regs ~80 so
// __launch_bounds__(256,6) (cap 85) fits spill-free -> 6 blocks/CU.
// Xp stored bf16, channel-interleaved: dword d = n*64 + o holds {ch0 lo, ch1 hi}.
#define GMT  64
#define BLDA2 136
#define GEMM_NB  ((N_NODES + GMT - 1) / GMT)      // 1563
#define BUILD_BX ((E_EDGE / 8 + 255) / 256)       // 391
#define BUILD_TOT (BUILD_BX * T_ET)               // 1564
__global__ __launch_bounds__(256, 6)
void fused_gemm_build(const float* __restrict__ X, const short* __restrict__ Bt,
                      short* __restrict__ Xp,
                      const int* __restrict__ edge_index,
                      const float* __restrict__ edge_value,
                      const int* __restrict__ rid,
                      int* __restrict__ counts,
                      unsigned long long* __restrict__ records) {
    __shared__ short Bl[64][BLDA2];    // 17.4 KB: 64 output-rows x 128 k per stage
    int tid = threadIdx.x;
    int bx = blockIdx.x;
    if (bx < GEMM_NB) {
        int w = tid >> 6, lane = tid & 63;
        int quad = lane >> 4, l15 = lane & 15;
        int m0 = bx * GMT + w * 16;
        int arow = m0 + l15;
        if (arow >= N_NODES) arow = N_NODES - 1;
        const float* xrow = X + (size_t)arow * W_INF;
        floatx4 acc[C_CH][4] = {};
        #pragma unroll 1
        for (int kh = 0; kh < 2; kh++) {          // K-half: addresses only
            // A strip for this K-half: 4 chunks x 8 bf16 = 16 VGPRs
            bf16x8 af[4];
            #pragma unroll
            for (int kc = 0; kc < 4; kc++) {
                int kb = kh * 128 + kc * 32 + quad * 8;
                float4 v0 = *(const float4*)&xrow[kb];
                float4 v1 = *(const float4*)&xrow[kb + 4];
                af[kc][0] = f2bf(v0.x); af[kc][1] = f2bf(v0.y);
                af[kc][2] = f2bf(v0.z); af[kc][3] = f2bf(v0.w);
                af[kc][4] = f2bf(v1.x); af[kc][5] = f2bf(v1.y);
                af[kc][6] = f2bf(v1.z); af[kc][7] = f2bf(v1.w);
            }
            #pragma unroll
            for (int c = 0; c < C_CH; c++) {      // fully unrolled: acc static
                if (kh | c) __syncthreads();      // protect re-stage
                // stage channel c, K-half kh: 64 rows x 128 k (1024 x 16B chunks)
                #pragma unroll
                for (int l = 0; l < 4; l++) {
                    int idx = tid + l * 256;
                    int r = idx >> 4;
                    int kp = (idx & 15) * 8;
                    *(bf16x8*)&Bl[r][kp] =
                        *(const bf16x8*)&Bt[(size_t)(c * 64 + r) * W_INF + kh * 128 + kp];
                }
                __syncthreads();
                #pragma unroll
                for (int kc = 0; kc < 4; kc++) {
                    int kb = kc * 32 + quad * 8;
                    #pragma unroll
                    for (int nt = 0; nt < 4; nt++) {
                        bf16x8 b = *(bf16x8*)&Bl[nt * 16 + l15][kb];
                        acc[c][nt] =
                            __builtin_amdgcn_mfma_f32_16x16x32_bf16(af[kc], b, acc[c][nt], 0, 0, 0);
                    }
                }
            }
        }
        // D layout: o = nt*16 + l15; m = m0 + quad*4 + r. Pack both channels.
        #pragma unroll
        for (int nt = 0; nt < 4; nt++) {
            int o = nt * 16 + l15;
            #pragma unroll
            for (int r = 0; r < 4; r++) {
                int m = m0 + quad * 4 + r;
                if (m < N_NODES) {
                    unsigned pk = (unsigned)(unsigned short)f2bf(acc[0][nt][r])
                                | ((unsigned)(unsigned short)f2bf(acc[1][nt][r]) << 16);
                    *(unsigned*)&Xp[(size_t)m * (C_CH * W_OUTF) + o * 2] = pk;
                }
            }
        }
    } else {
        int bb = bx - GEMM_NB;                    // 0..BUILD_TOT-1
        int t = bb / BUILD_BX;
        int i = (bb - t * BUILD_BX) * 256 + tid;  // oct-edge index
        if (i >= E_EDGE / 8) return;
        int e = i * 8;
        const int*   rbase = &edge_index[(size_t)(t * 2 + 0) * E_EDGE + e];
        const int*   cbase = &edge_index[(size_t)(t * 2 + 1) * E_EDGE + e];
        const float* vbase = &edge_value[(size_t)t * E_EDGE + e];
        int4   r4a = *(const int4*)  &rbase[0], r4b = *(const int4*)  &rbase[4];
        int4   c4a = *(const int4*)  &cbase[0], c4b = *(const int4*)  &cbase[4];
        float4 v4a = *(const float4*)&vbase[0], v4b = *(const float4*)&vbase[4];
        int rows[8] = {r4a.x, r4a.y, r4a.z, r4a.w, r4b.x, r4b.y, r4b.z, r4b.w};
        int cols[8] = {c4a.x, c4a.y, c4a.z, c4a.w, c4b.x, c4b.y, c4b.z, c4b.w};
        float evv[8] = {v4a.x, v4a.y, v4a.z, v4a.w, v4b.x, v4b.y, v4b.z, v4b.w};
        int ids[8];
        #pragma unroll
        for (int j = 0; j < 8; j++) ids[j] = rid[rows[j]];
        #pragma unroll
        for (int j = 0; j < 8; j++) {
            if (ids[j] >= 0) {
                int p = atomicAdd(&counts[ids[j]], 1);
                if (p < MAXDEG) {
                    unsigned long long rec =
                        (unsigned long long)(unsigned)(cols[j] | (t << 20)) |
                        ((unsigned long long)__float_as_uint(evv[j]) << 32);
                    records[(size_t)ids[j] * MAXDEG + p] = rec;
                }
            }
        }
    }
}

// ---------- gather + relu fuse: one wave per row, both channels per lane ----------
// Xp dword d = node*64 + lane holds both channels -> one coalesced 256B read/edge.
// 8-deep unroll: one full 64B record line + 8 independent row reads in flight.
__global__ void gather_kernel(const int* __restrict__ row_list,
                              const int* __restrict__ counts,
                              const unsigned long long* __restrict__ records,
                              const float* __restrict__ filt,
                              const short* __restrict__ Xp,
                              float* __restrict__ Hcat,
                              const int* __restrict__ nrows_ptr) {
    int w = threadIdx.x >> 6, lane = threadIdx.x & 63;
    int b = blockIdx.x * 4 + w;
    if (b >= *nrows_ptr) return;
    float f0[T_ET], f1[T_ET];
    #pragma unroll
    for (int t = 0; t < T_ET; t++) { f0[t] = filt[t]; f1[t] = filt[T_ET + t]; }
    int n = row_list[b];
    int cnt = counts[b]; if (cnt > MAXDEG) cnt = MAXDEG;
    const unsigned long long* rec = records + (size_t)b * MAXDEG;
    const unsigned* xb = (const unsigned*)Xp + lane;
    float a0 = 0.f, a1 = 0.f;
    int p = 0;
    for (; p + 7 < cnt; p += 8) {
        unsigned long long rr[8];
        #pragma unroll
        for (int j = 0; j < 8; j++) rr[j] = rec[p + j];
        unsigned q[8];
        #pragma unroll
        for (int j = 0; j < 8; j++)
            q[j] = xb[(size_t)((unsigned)rr[j] & 0xFFFFF) * 64];
        #pragma unroll
        for (int j = 0; j < 8; j++) {
            int t = (int)((unsigned)rr[j] >> 20);
            float e = __uint_as_float((unsigned)(rr[j] >> 32));
            a0 += e * f0[t] * bflo(q[j]);
            a1 += e * f1[t] * bfhi(q[j]);
        }
    }
    for (; p + 3 < cnt; p += 4) {
        unsigned long long rr[4];
        #pragma unroll
        for (int j = 0; j < 4; j++) rr[j] = rec[p + j];
        #pragma unroll
        for (int j = 0; j < 4; j++) {
            unsigned q = xb[(size_t)((unsigned)rr[j] & 0xFFFFF) * 64];
            int t = (int)((unsigned)rr[j] >> 20);
            float e = __uint_as_float((unsigned)(rr[j] >> 32));
            a0 += e * f0[t] * bflo(q);
            a1 += e * f1[t] * bfhi(q);
        }
    }
    for (; p < cnt; p++) {
        unsigned long long r0 = rec[p];
        int k0 = (int)(unsigned)r0;
        float e0 = __uint_as_float((unsigned)(r0 >> 32));
        unsigned q0 = xb[(size_t)(k0 & 0xFFFFF) * 64];
        int t0 = k0 >> 20;
        a0 += e0 * f0[t0] * bflo(q0);
        a1 += e0 * f1[t0] * bfhi(q0);
    }
    unsigned qn = xb[(size_t)n * 64];
    float h0 = BETA * bflo(qn) + (1.f - BETA) * a0;
    float h1 = BETA * bfhi(qn) + (1.f - BETA) * a1;
    Hcat[(size_t)b * (C_CH * W_OUTF) + lane]          = fmaxf(h0, 0.f);
    Hcat[(size_t)b * (C_CH * W_OUTF) + W_OUTF + lane] = fmaxf(h1, 0.f);
}

// ---------- head: reads compacted Hcat via rid ----------
#define HTGT 16
__global__ void head_kernel(const float* __restrict__ Hcat,
                            const int* __restrict__ rid,
                            const float* __restrict__ W1,
                            const float* __restrict__ b1,
                            const float* __restrict__ linW,
                            const float* __restrict__ linb,
                            const int* __restrict__ target_x,
                            const int* __restrict__ target,
                            float* __restrict__ out) {
    __shared__ float w1s[C_CH * W_OUTF][W_OUTF + 1];
    __shared__ float hcat_s[4][C_CH * W_OUTF];
    __shared__ float loss_s[4];
    int tid = threadIdx.x;
    for (int i = tid; i < W_OUTF * C_CH * W_OUTF; i += 256) {
        int o = i >> 7, k = i & 127;
        w1s[k][o] = W1[i];
    }
    int wave = tid >> 6, lane = tid & 63;
    float l0 = linW[0 * W_OUTF + lane], l1 = linW[1 * W_OUTF + lane];
    float l2 = linW[2 * W_OUTF + lane], l3 = linW[3 * W_OUTF + lane];
    float lb0 = linb[0], lb1 = linb[1], lb2 = linb[2], lb3 = linb[3];
    float bias = b1[lane];
    float lsum = 0.f;
    __syncthreads();
    for (int it = 0; it < HTGT / 4; it++) {
        int m = blockIdx.x * HTGT + it * 4 + wave;
        int row = target_x[m];
        int id = rid[row];
        hcat_s[wave][lane]      = Hcat[(size_t)id * (C_CH * W_OUTF) + lane];
        hcat_s[wave][64 + lane] = Hcat[(size_t)id * (C_CH * W_OUTF) + 64 + lane];
        __syncthreads();
        float acc = bias;
        #pragma unroll 8
        for (int k = 0; k < C_CH * W_OUTF; k++) acc += hcat_s[wave][k] * w1s[k][lane];
        float h2 = fmaxf(acc, 0.f);
        float p0 = l0 * h2, p1 = l1 * h2, p2 = l2 * h2, p3 = l3 * h2;
        #pragma unroll
        for (int off = 32; off > 0; off >>= 1) {
            p0 += __shfl_xor(p0, off);
            p1 += __shfl_xor(p1, off);
            p2 += __shfl_xor(p2, off);
            p3 += __shfl_xor(p3, off);
        }
        if (lane == 0) {
            float y[NUM_CLS];
            y[0] = p0 + lb0; y[1] = p1 + lb1; y[2] = p2 + lb2; y[3] = p3 + lb3;
            float mx = fmaxf(fmaxf(y[0], y[1]), fmaxf(y[2], y[3]));
            float s = 0.f;
            #pragma unroll
            for (int k = 0; k < NUM_CLS; k++) s += expf(y[k] - mx);
            float lse = mx + logf(s);
            #pragma unroll
            for (int k = 0; k < NUM_CLS; k++) out[1 + (size_t)m * NUM_CLS + k] = y[k];
            int tg = target[m];
            lsum += lse - y[tg];
        }
        __syncthreads();
    }
    if (lane == 0) loss_s[wave] = lsum;
    __syncthreads();
    if (tid == 0) {
        float L = loss_s[0] + loss_s[1] + loss_s[2] + loss_s[3];
        atomicAdd(&out[0], L * (1.0f / (float)M_TGT));
    }
}

extern "C" void kernel_launch(void* const* d_in, const int* in_sizes, int n_in,
                              void* d_out, int out_size, void* d_ws, size_t ws_size,
                              hipStream_t stream) {
    const float* X           = (const float*)d_in[0];
    const float* edge_value  = (const float*)d_in[1];
    const float* Ws          = (const float*)d_in[2];
    const float* conv_weight = (const float*)d_in[3];
    const float* linear1_W   = (const float*)d_in[4];
    const float* linear1_b   = (const float*)d_in[5];
    const float* lin_W       = (const float*)d_in[6];
    const float* lin_b       = (const float*)d_in[7];
    const int*   edge_index  = (const int*)d_in[8];
    const int*   target_x    = (const int*)d_in[9];
    const int*   target      = (const int*)d_in[10];
    float* out = (float*)d_out;

    char* ws = (char*)d_ws;
    size_t off = 0;
    float* filt  = (float*)(ws + off); off += 256;
    size_t xbytes = (size_t)N_NODES * C_CH * W_OUTF * sizeof(short);  // 25.6 MB bf16
    short* Xp    = (short*)(ws + off); off += xbytes;
    float* Hcat  = (float*)(ws + off); off += (size_t)M_TGT * C_CH * W_OUTF * sizeof(float);
    unsigned long long* records = (unsigned long long*)(ws + off);
    off += (size_t)M_TGT * MAXDEG * sizeof(unsigned long long);       // 15.4 MB
    short* Bt    = (short*)(ws + off); off += (size_t)C_CH * W_OUTF * W_INF * sizeof(short);
    int*   rid   = (int*)  (ws + off); off += (size_t)N_NODES * sizeof(int);
    int*   row_list = (int*)(ws + off); off += (size_t)M_TGT * sizeof(int);
    int*   counts   = (int*)(ws + off); off += (size_t)M_TGT * sizeof(int);
    int*   nrows    = (int*)(ws + off); off += 256;

    hipMemsetAsync(rid, 0xFF, (size_t)N_NODES * sizeof(int), stream);   // -1

    setup_kernel<<<128, 256, 0, stream>>>(Ws, conv_weight, target_x, Bt, filt, rid, nrows, out);
    compact_kernel<<<(N_NODES + 255) / 256, 256, 0, stream>>>(rid, row_list, nrows, counts);
    fused_gemm_build<<<GEMM_NB + BUILD_TOT, 256, 0, stream>>>(
        X, Bt, Xp, edge_index, edge_value, rid, counts, records);
    gather_kernel<<<(M_TGT + 3) / 4, 256, 0, stream>>>(row_list, counts, records, filt, Xp, Hcat, nrows);
    head_kernel<<<M_TGT / HTGT, 256, 0, stream>>>(Hcat, rid, linear1_W, linear1_b, lin_W, lin_b,
                                                  target_x, target, out);
}

// Round 5
// 299.332 us; speedup vs baseline: 1.1760x; 1.0690x over previous
//
#include <hip/hip_runtime.h>

#define N_NODES 100000
#define W_INF   256
#define W_OUTF  64
#define C_CH    2
#define T_ET    4
#define E_EDGE  800000
#define NUM_CLS 4
#define M_TGT   20000
#define BETA    0.5f
#define MAXDEG  96

typedef __attribute__((ext_vector_type(8))) short bf16x8;
typedef __attribute__((ext_vector_type(4))) float floatx4;

__device__ inline short f2bf(float f) {
    unsigned u = __builtin_bit_cast(unsigned, f);
    u += 0x7FFF + ((u >> 16) & 1);          // RNE
    return (short)(u >> 16);
}
// packed dword q = (bf16 ch0) | (bf16 ch1 << 16)
__device__ inline float bflo(unsigned q) { return __builtin_bit_cast(float, q << 16); }
__device__ inline float bfhi(unsigned q) { return __builtin_bit_cast(float, q & 0xFFFF0000u); }

// ---------- setup: softmax(filt) + Bt convert + mark rid + zero scalars ----------
__global__ void setup_kernel(const float* __restrict__ Ws,
                             const float* __restrict__ conv_weight,
                             const int* __restrict__ target_x,
                             short* __restrict__ Bt, float* __restrict__ filt,
                             int* __restrict__ rid, int* __restrict__ nrows,
                             float* __restrict__ out) {
    int i = blockIdx.x * 256 + threadIdx.x;
    if (i == 0) { *nrows = 0; out[0] = 0.f; }
    if (i < C_CH) {
        int c = i;
        float mx = -1e30f;
        for (int t = 0; t < T_ET; t++) mx = fmaxf(mx, conv_weight[c * T_ET + t]);
        float e[T_ET];
        float s = 0.f;
        for (int t = 0; t < T_ET; t++) { e[t] = expf(conv_weight[c * T_ET + t] - mx); s += e[t]; }
        for (int t = 0; t < T_ET; t++) filt[c * T_ET + t] = e[t] / s;
    }
    if (i < C_CH * W_OUTF * W_INF) {
        int co = i >> 8, k = i & 255;
        int c = co >> 6, o = co & 63;
        Bt[i] = f2bf(Ws[((size_t)c * W_INF + k) * W_OUTF + o]);
    }
    if (i < M_TGT) rid[target_x[i]] = -2;
}

// ---------- compact flagged rows (wave-aggregated atomic) + zero counts ----------
__global__ void compact_kernel(int* __restrict__ rid, int* __restrict__ row_list,
                               int* __restrict__ nrows, int* __restrict__ counts) {
    int n = blockIdx.x * blockDim.x + threadIdx.x;
    if (n < M_TGT) counts[n] = 0;          // consumed by fused build (next dispatch)
    int lane = threadIdx.x & 63;
    bool flag = (n < N_NODES) && (rid[n] == -2);
    unsigned long long mask = __ballot(flag);
    int base = 0;
    if (lane == 0 && mask) base = atomicAdd(nrows, __popcll(mask));
    base = __shfl(base, 0);
    if (flag) {
        int id = base + __popcll(mask & ((1ULL << lane) - 1ULL));
        rid[n] = id;
        row_list[id] = n;
    }
}

// ---------- fused: MFMA gemm (even blocks) + edge binning (odd blocks) ----------
// R4 lesson: (256,6)'s ~85-reg cap still spilled (~15 regs, VGPR_Count 40,
// +12MB traffic). (256,4) = 128-reg cap is definitively spill-free; occupancy
// is then reg-bound at ~5 blocks/CU (LDS 17.4KB doesn't bind).
// Even/odd interleave: gemm waves (cold X-load latency) and build waves
// (random rid-load + atomic latency) co-reside per CU -> two independent
// latency streams per scheduler (m114). Clean test now that spill is gone.
// Xp stored bf16, channel-interleaved: dword d = n*64 + o holds {ch0 lo, ch1 hi}.
#define GMT  64
#define BLDA2 136
#define GEMM_NB  ((N_NODES + GMT - 1) / GMT)      // 1563
#define BUILD_BX ((E_EDGE / 8 + 255) / 256)       // 391
#define BUILD_TOT (BUILD_BX * T_ET)               // 1564
__global__ __launch_bounds__(256, 4)
void fused_gemm_build(const float* __restrict__ X, const short* __restrict__ Bt,
                      short* __restrict__ Xp,
                      const int* __restrict__ edge_index,
                      const float* __restrict__ edge_value,
                      const int* __restrict__ rid,
                      int* __restrict__ counts,
                      unsigned long long* __restrict__ records) {
    __shared__ short Bl[64][BLDA2];    // 17.4 KB: 64 output-rows x 128 k per stage
    int tid = threadIdx.x;
    int bx = blockIdx.x;
    if ((bx & 1) == 0) {
        int g = bx >> 1;
        if (g >= GEMM_NB) return;
        int w = tid >> 6, lane = tid & 63;
        int quad = lane >> 4, l15 = lane & 15;
        int m0 = g * GMT + w * 16;
        int arow = m0 + l15;
        if (arow >= N_NODES) arow = N_NODES - 1;
        const float* xrow = X + (size_t)arow * W_INF;
        floatx4 acc[C_CH][4] = {};
        #pragma unroll 1
        for (int kh = 0; kh < 2; kh++) {          // K-half: addresses only
            // A strip for this K-half: 4 chunks x 8 bf16 = 16 VGPRs
            bf16x8 af[4];
            #pragma unroll
            for (int kc = 0; kc < 4; kc++) {
                int kb = kh * 128 + kc * 32 + quad * 8;
                float4 v0 = *(const float4*)&xrow[kb];
                float4 v1 = *(const float4*)&xrow[kb + 4];
                af[kc][0] = f2bf(v0.x); af[kc][1] = f2bf(v0.y);
                af[kc][2] = f2bf(v0.z); af[kc][3] = f2bf(v0.w);
                af[kc][4] = f2bf(v1.x); af[kc][5] = f2bf(v1.y);
                af[kc][6] = f2bf(v1.z); af[kc][7] = f2bf(v1.w);
            }
            #pragma unroll
            for (int c = 0; c < C_CH; c++) {      // fully unrolled: acc static
                if (kh | c) __syncthreads();      // protect re-stage
                // stage channel c, K-half kh: 64 rows x 128 k (1024 x 16B chunks)
                #pragma unroll
                for (int l = 0; l < 4; l++) {
                    int idx = tid + l * 256;
                    int r = idx >> 4;
                    int kp = (idx & 15) * 8;
                    *(bf16x8*)&Bl[r][kp] =
                        *(const bf16x8*)&Bt[(size_t)(c * 64 + r) * W_INF + kh * 128 + kp];
                }
                __syncthreads();
                #pragma unroll
                for (int kc = 0; kc < 4; kc++) {
                    int kb = kc * 32 + quad * 8;
                    #pragma unroll
                    for (int nt = 0; nt < 4; nt++) {
                        bf16x8 b = *(bf16x8*)&Bl[nt * 16 + l15][kb];
                        acc[c][nt] =
                            __builtin_amdgcn_mfma_f32_16x16x32_bf16(af[kc], b, acc[c][nt], 0, 0, 0);
                    }
                }
            }
        }
        // D layout: o = nt*16 + l15; m = m0 + quad*4 + r. Pack both channels.
        #pragma unroll
        for (int nt = 0; nt < 4; nt++) {
            int o = nt * 16 + l15;
            #pragma unroll
            for (int r = 0; r < 4; r++) {
                int m = m0 + quad * 4 + r;
                if (m < N_NODES) {
                    unsigned pk = (unsigned)(unsigned short)f2bf(acc[0][nt][r])
                                | ((unsigned)(unsigned short)f2bf(acc[1][nt][r]) << 16);
                    *(unsigned*)&Xp[(size_t)m * (C_CH * W_OUTF) + o * 2] = pk;
                }
            }
        }
    } else {
        int bb = bx >> 1;                         // 0..BUILD_TOT-1
        if (bb >= BUILD_TOT) return;
        int t = bb / BUILD_BX;
        int i = (bb - t * BUILD_BX) * 256 + tid;  // oct-edge index
        if (i >= E_EDGE / 8) return;
        int e = i * 8;
        const int*   rbase = &edge_index[(size_t)(t * 2 + 0) * E_EDGE + e];
        const int*   cbase = &edge_index[(size_t)(t * 2 + 1) * E_EDGE + e];
        const float* vbase = &edge_value[(size_t)t * E_EDGE + e];
        int4   r4a = *(const int4*)  &rbase[0], r4b = *(const int4*)  &rbase[4];
        int4   c4a = *(const int4*)  &cbase[0], c4b = *(const int4*)  &cbase[4];
        float4 v4a = *(const float4*)&vbase[0], v4b = *(const float4*)&vbase[4];
        int rows[8] = {r4a.x, r4a.y, r4a.z, r4a.w, r4b.x, r4b.y, r4b.z, r4b.w};
        int cols[8] = {c4a.x, c4a.y, c4a.z, c4a.w, c4b.x, c4b.y, c4b.z, c4b.w};
        float evv[8] = {v4a.x, v4a.y, v4a.z, v4a.w, v4b.x, v4b.y, v4b.z, v4b.w};
        int ids[8];
        #pragma unroll
        for (int j = 0; j < 8; j++) ids[j] = rid[rows[j]];
        #pragma unroll
        for (int j = 0; j < 8; j++) {
            if (ids[j] >= 0) {
                int p = atomicAdd(&counts[ids[j]], 1);
                if (p < MAXDEG) {
                    unsigned long long rec =
                        (unsigned long long)(unsigned)(cols[j] | (t << 20)) |
                        ((unsigned long long)__float_as_uint(evv[j]) << 32);
                    records[(size_t)ids[j] * MAXDEG + p] = rec;
                }
            }
        }
    }
}

// ---------- gather + relu fuse: one wave per row, both channels per lane ----------
// Xp dword d = node*64 + lane holds both channels -> one coalesced 256B read/edge.
// 8-deep unroll: one full 64B record line + 8 independent row reads in flight.
__global__ void gather_kernel(const int* __restrict__ row_list,
                              const int* __restrict__ counts,
                              const unsigned long long* __restrict__ records,
                              const float* __restrict__ filt,
                              const short* __restrict__ Xp,
                              float* __restrict__ Hcat,
                              const int* __restrict__ nrows_ptr) {
    int w = threadIdx.x >> 6, lane = threadIdx.x & 63;
    int b = blockIdx.x * 4 + w;
    if (b >= *nrows_ptr) return;
    float f0[T_ET], f1[T_ET];
    #pragma unroll
    for (int t = 0; t < T_ET; t++) { f0[t] = filt[t]; f1[t] = filt[T_ET + t]; }
    int n = row_list[b];
    int cnt = counts[b]; if (cnt > MAXDEG) cnt = MAXDEG;
    const unsigned long long* rec = records + (size_t)b * MAXDEG;
    const unsigned* xb = (const unsigned*)Xp + lane;
    float a0 = 0.f, a1 = 0.f;
    int p = 0;
    for (; p + 7 < cnt; p += 8) {
        unsigned long long rr[8];
        #pragma unroll
        for (int j = 0; j < 8; j++) rr[j] = rec[p + j];
        unsigned q[8];
        #pragma unroll
        for (int j = 0; j < 8; j++)
            q[j] = xb[(size_t)((unsigned)rr[j] & 0xFFFFF) * 64];
        #pragma unroll
        for (int j = 0; j < 8; j++) {
            int t = (int)((unsigned)rr[j] >> 20);
            float e = __uint_as_float((unsigned)(rr[j] >> 32));
            a0 += e * f0[t] * bflo(q[j]);
            a1 += e * f1[t] * bfhi(q[j]);
        }
    }
    for (; p + 3 < cnt; p += 4) {
        unsigned long long rr[4];
        #pragma unroll
        for (int j = 0; j < 4; j++) rr[j] = rec[p + j];
        #pragma unroll
        for (int j = 0; j < 4; j++) {
            unsigned q = xb[(size_t)((unsigned)rr[j] & 0xFFFFF) * 64];
            int t = (int)((unsigned)rr[j] >> 20);
            float e = __uint_as_float((unsigned)(rr[j] >> 32));
            a0 += e * f0[t] * bflo(q);
            a1 += e * f1[t] * bfhi(q);
        }
    }
    for (; p < cnt; p++) {
        unsigned long long r0 = rec[p];
        int k0 = (int)(unsigned)r0;
        float e0 = __uint_as_float((unsigned)(r0 >> 32));
        unsigned q0 = xb[(size_t)(k0 & 0xFFFFF) * 64];
        int t0 = k0 >> 20;
        a0 += e0 * f0[t0] * bflo(q0);
        a1 += e0 * f1[t0] * bfhi(q0);
    }
    unsigned qn = xb[(size_t)n * 64];
    float h0 = BETA * bflo(qn) + (1.f - BETA) * a0;
    float h1 = BETA * bfhi(qn) + (1.f - BETA) * a1;
    Hcat[(size_t)b * (C_CH * W_OUTF) + lane]          = fmaxf(h0, 0.f);
    Hcat[(size_t)b * (C_CH * W_OUTF) + W_OUTF + lane] = fmaxf(h1, 0.f);
}

// ---------- head: reads compacted Hcat via rid ----------
#define HTGT 16
__global__ void head_kernel(const float* __restrict__ Hcat,
                            const int* __restrict__ rid,
                            const float* __restrict__ W1,
                            const float* __restrict__ b1,
                            const float* __restrict__ linW,
                            const float* __restrict__ linb,
                            const int* __restrict__ target_x,
                            const int* __restrict__ target,
                            float* __restrict__ out) {
    __shared__ float w1s[C_CH * W_OUTF][W_OUTF + 1];
    __shared__ float hcat_s[4][C_CH * W_OUTF];
    __shared__ float loss_s[4];
    int tid = threadIdx.x;
    for (int i = tid; i < W_OUTF * C_CH * W_OUTF; i += 256) {
        int o = i >> 7, k = i & 127;
        w1s[k][o] = W1[i];
    }
    int wave = tid >> 6, lane = tid & 63;
    float l0 = linW[0 * W_OUTF + lane], l1 = linW[1 * W_OUTF + lane];
    float l2 = linW[2 * W_OUTF + lane], l3 = linW[3 * W_OUTF + lane];
    float lb0 = linb[0], lb1 = linb[1], lb2 = linb[2], lb3 = linb[3];
    float bias = b1[lane];
    float lsum = 0.f;
    __syncthreads();
    for (int it = 0; it < HTGT / 4; it++) {
        int m = blockIdx.x * HTGT + it * 4 + wave;
        int row = target_x[m];
        int id = rid[row];
        hcat_s[wave][lane]      = Hcat[(size_t)id * (C_CH * W_OUTF) + lane];
        hcat_s[wave][64 + lane] = Hcat[(size_t)id * (C_CH * W_OUTF) + 64 + lane];
        __syncthreads();
        float acc = bias;
        #pragma unroll 8
        for (int k = 0; k < C_CH * W_OUTF; k++) acc += hcat_s[wave][k] * w1s[k][lane];
        float h2 = fmaxf(acc, 0.f);
        float p0 = l0 * h2, p1 = l1 * h2, p2 = l2 * h2, p3 = l3 * h2;
        #pragma unroll
        for (int off = 32; off > 0; off >>= 1) {
            p0 += __shfl_xor(p0, off);
            p1 += __shfl_xor(p1, off);
            p2 += __shfl_xor(p2, off);
            p3 += __shfl_xor(p3, off);
        }
        if (lane == 0) {
            float y[NUM_CLS];
            y[0] = p0 + lb0; y[1] = p1 + lb1; y[2] = p2 + lb2; y[3] = p3 + lb3;
            float mx = fmaxf(fmaxf(y[0], y[1]), fmaxf(y[2], y[3]));
            float s = 0.f;
            #pragma unroll
            for (int k = 0; k < NUM_CLS; k++) s += expf(y[k] - mx);
            float lse = mx + logf(s);
            #pragma unroll
            for (int k = 0; k < NUM_CLS; k++) out[1 + (size_t)m * NUM_CLS + k] = y[k];
            int tg = target[m];
            lsum += lse - y[tg];
        }
        __syncthreads();
    }
    if (lane == 0) loss_s[wave] = lsum;
    __syncthreads();
    if (tid == 0) {
        float L = loss_s[0] + loss_s[1] + loss_s[2] + loss_s[3];
        atomicAdd(&out[0], L * (1.0f / (float)M_TGT));
    }
}

extern "C" void kernel_launch(void* const* d_in, const int* in_sizes, int n_in,
                              void* d_out, int out_size, void* d_ws, size_t ws_size,
                              hipStream_t stream) {
    const float* X           = (const float*)d_in[0];
    const float* edge_value  = (const float*)d_in[1];
    const float* Ws          = (const float*)d_in[2];
    const float* conv_weight = (const float*)d_in[3];
    const float* linear1_W   = (const float*)d_in[4];
    const float* linear1_b   = (const float*)d_in[5];
    const float* lin_W       = (const float*)d_in[6];
    const float* lin_b       = (const float*)d_in[7];
    const int*   edge_index  = (const int*)d_in[8];
    const int*   target_x    = (const int*)d_in[9];
    const int*   target      = (const int*)d_in[10];
    float* out = (float*)d_out;

    char* ws = (char*)d_ws;
    size_t off = 0;
    float* filt  = (float*)(ws + off); off += 256;
    size_t xbytes = (size_t)N_NODES * C_CH * W_OUTF * sizeof(short);  // 25.6 MB bf16
    short* Xp    = (short*)(ws + off); off += xbytes;
    float* Hcat  = (float*)(ws + off); off += (size_t)M_TGT * C_CH * W_OUTF * sizeof(float);
    unsigned long long* records = (unsigned long long*)(ws + off);
    off += (size_t)M_TGT * MAXDEG * sizeof(unsigned long long);       // 15.4 MB
    short* Bt    = (short*)(ws + off); off += (size_t)C_CH * W_OUTF * W_INF * sizeof(short);
    int*   rid   = (int*)  (ws + off); off += (size_t)N_NODES * sizeof(int);
    int*   row_list = (int*)(ws + off); off += (size_t)M_TGT * sizeof(int);
    int*   counts   = (int*)(ws + off); off += (size_t)M_TGT * sizeof(int);
    int*   nrows    = (int*)(ws + off); off += 256;

    hipMemsetAsync(rid, 0xFF, (size_t)N_NODES * sizeof(int), stream);   // -1

    setup_kernel<<<128, 256, 0, stream>>>(Ws, conv_weight, target_x, Bt, filt, rid, nrows, out);
    compact_kernel<<<(N_NODES + 255) / 256, 256, 0, stream>>>(rid, row_list, nrows, counts);
    fused_gemm_build<<<2 * BUILD_TOT, 256, 0, stream>>>(
        X, Bt, Xp, edge_index, edge_value, rid, counts, records);
    gather_kernel<<<(M_TGT + 3) / 4, 256, 0, stream>>>(row_list, counts, records, filt, Xp, Hcat, nrows);
    head_kernel<<<M_TGT / HTGT, 256, 0, stream>>>(Hcat, rid, linear1_W, linear1_b, lin_W, lin_b,
                                                  target_x, target, out);
}